// Round 13
// baseline (956.326 us; speedup 1.0000x reference)
//
#include <hip/hip_runtime.h>

#define NEG_SLOPE 0.2f

static __device__ __forceinline__ unsigned short f2bf(float f) {
    unsigned u = __float_as_uint(f);
    unsigned r = (u + 0x7fffu + ((u >> 16) & 1u)) >> 16;   // RNE
    return (unsigned short)r;
}
static __device__ __forceinline__ float bflo(unsigned z) {
    return __uint_as_float((z & 0xffffu) << 16);
}
static __device__ __forceinline__ float bfhi(unsigned z) {
    return __uint_as_float(z & 0xffff0000u);
}

#define PREP_B 66   // blocks for prep part (128*128+512 = 16896 threads)

// ---- K1: prep (Wc, avec)  ||  count8 (per (64-chunk, edge-class) histogram) ----
__global__ __launch_bounds__(256) void prep_count_kernel(
    const float* __restrict__ Wl, const float* __restrict__ Wout,
    const float* __restrict__ attL, const float* __restrict__ attR,
    float* __restrict__ Wc, float* __restrict__ avec,
    const int* __restrict__ ei, int E, int Etot, int* __restrict__ cnt8)
{
    int bid = blockIdx.x;
    if (bid < PREP_B) {
        int idx = bid * 256 + threadIdx.x;
        if (idx < 128 * 128) {
            int k = idx >> 7, c = idx & 127;
            int h = c >> 6, cc = c & 63;
            const float* wl = Wl + k * 128 + h * 64;
            const float* wo = Wout + (h * 64) * 64 + cc;
            float s = 0.f;
#pragma unroll 8
            for (int m = 0; m < 64; ++m) s += wl[m] * wo[m * 64];
            Wc[k * 128 + c] = s;
        } else if (idx < 128 * 128 + 512) {
            int r = idx - 128 * 128;
            int k = r >> 2, t = r & 3;
            int h = t & 1;
            const float* av = ((t < 2) ? attL : attR) + h * 64;
            const float* wl = Wl + k * 128 + h * 64;
            float s = 0.f;
#pragma unroll 8
            for (int m = 0; m < 64; ++m) s += wl[m] * av[m];
            avec[k * 4 + t] = s;
        }
    } else {
        int e = (bid - PREP_B) * 256 + threadIdx.x;
        if (e >= Etot) return;
        int dst = (e < E) ? ei[E + e] : (e - E);
        atomicAdd(&cnt8[(dst >> 6) * 8 + ((e >> 8) & 7)], 1);
    }
}

// ---- K2: zproj (Z bf16, AL/AR)  ||  one block: exclusive scan of cnt8 ----
__global__ __launch_bounds__(256, 4) void zproj_scan_kernel(
    const float* __restrict__ x, const float* __restrict__ Wc,
    const float* __restrict__ avec, int N, int ZB, int NSEG, int Etot,
    unsigned short* __restrict__ Z, float* __restrict__ AL, float* __restrict__ AR,
    const int* __restrict__ cnt8, int* __restrict__ B8, int* __restrict__ cptr)
{
    __shared__ float xs[64 * 136];
    __shared__ float avs[128 * 4];
    const int tid = threadIdx.x;

    if ((int)blockIdx.x >= ZB) {
        // ----- segment scan: B8[i] = exclusive prefix of cnt8; cptr = copy -----
        __shared__ int part[256];
        const int PER = (NSEG + 255) / 256;          // 25
        int lo = tid * PER;
        int hi = lo + PER; if (hi > NSEG) hi = NSEG;
        int s = 0;
        for (int i = lo; i < hi; ++i) s += cnt8[i];
        part[tid] = s; __syncthreads();
#pragma unroll
        for (int o = 1; o < 256; o <<= 1) {
            int add = (tid >= o) ? part[tid - o] : 0;
            __syncthreads();
            part[tid] += add;
            __syncthreads();
        }
        int run = part[tid] - s;                      // exclusive prefix
        for (int i = lo; i < hi; ++i) {
            B8[i] = run; cptr[i] = run;
            run += cnt8[i];
        }
        if (tid == 255) B8[NSEG] = Etot;
        return;
    }

    // ----- zproj -----
    const int row0 = blockIdx.x * 64;
    const float4* x4 = (const float4*)x;
#pragma unroll
    for (int it = 0; it < 8; ++it) {
        int f4 = it * 256 + tid;           // 2048 float4 = 64 rows x 32 chunks
        int r = f4 >> 5, kq = f4 & 31;
        int rsrc = row0 + r; if (rsrc >= N) rsrc = N - 1;
        float4 v = x4[(size_t)rsrc * 32 + kq];
        *(float4*)&xs[r * 136 + kq * 4] = v;
    }
    if (tid < 128) *(float4*)&avs[tid * 4] = *(const float4*)&avec[tid * 4];
    __syncthreads();

    const int cg = tid & 31;   // cols cg*4..+3
    const int rg = tid >> 5;   // rows rg*8..+7
    const int c0 = cg * 4, r0 = rg * 8;
    float acc[8][4] = {};
    const float* wp = Wc + c0;
    for (int kc = 0; kc < 32; ++kc) {
        int k = kc * 4;
        float4 w0 = *(const float4*)&wp[(k + 0) * 128];
        float4 w1 = *(const float4*)&wp[(k + 1) * 128];
        float4 w2 = *(const float4*)&wp[(k + 2) * 128];
        float4 w3 = *(const float4*)&wp[(k + 3) * 128];
#pragma unroll
        for (int i = 0; i < 8; ++i) {
            float4 xv = *(const float4*)&xs[(r0 + i) * 136 + k];
            acc[i][0] += xv.x * w0.x + xv.y * w1.x + xv.z * w2.x + xv.w * w3.x;
            acc[i][1] += xv.x * w0.y + xv.y * w1.y + xv.z * w2.y + xv.w * w3.y;
            acc[i][2] += xv.x * w0.z + xv.y * w1.z + xv.z * w2.z + xv.w * w3.z;
            acc[i][3] += xv.x * w0.w + xv.y * w1.w + xv.z * w2.w + xv.w * w3.w;
        }
    }
#pragma unroll
    for (int i = 0; i < 8; ++i) {
        int row = row0 + r0 + i;
        if (row < N) {
            ushort4 zz;
            zz.x = f2bf(acc[i][0]); zz.y = f2bf(acc[i][1]);
            zz.z = f2bf(acc[i][2]); zz.w = f2bf(acc[i][3]);
            *(ushort4*)(Z + (size_t)row * 128 + c0) = zz;
        }
    }
    // alpha tail: one dot per thread (row = tid>>2, type = tid&3)
    {
        int row = tid >> 2, t = tid & 3;
        const float* xr = &xs[row * 136];
        float s = 0.f;
#pragma unroll 8
        for (int k = 0; k < 128; k += 4) {
            float4 xv = *(const float4*)&xr[k];
            s += xv.x * avs[(k + 0) * 4 + t] + xv.y * avs[(k + 1) * 4 + t]
               + xv.z * avs[(k + 2) * 4 + t] + xv.w * avs[(k + 3) * 4 + t];
        }
        int grow = row0 + row;
        if (grow < N) {
            if (t < 2) AL[grow * 2 + t] = s;
            else       AR[grow * 2 + (t - 2)] = s;
        }
    }
}

// ---- K3: fillb — append 4B record (src<<6|dstlo) to (chunk, class) segment ----
__global__ void fillb_kernel(const int* __restrict__ ei, int E, int Etot,
                             int* __restrict__ cptr, unsigned* __restrict__ edg)
{
    int e = blockIdx.x * 256 + threadIdx.x;
    if (e >= Etot) return;
    int src, dst;
    if (e < E) { src = ei[e]; dst = ei[E + e]; }
    else       { src = e - E; dst = e - E; }
    int pos = atomicAdd(&cptr[(dst >> 6) * 8 + ((e >> 8) & 7)], 1);
    edg[pos] = ((unsigned)src << 6) | (unsigned)(dst & 63);
}

// ---- K4: aggB — block per 64-node chunk, LDS accumulation ----
__global__ __launch_bounds__(256) void aggB_kernel(
    const int* __restrict__ B8, const unsigned* __restrict__ edg,
    const float* __restrict__ AL, const float* __restrict__ AR,
    const unsigned short* __restrict__ Z, const float* __restrict__ bias,
    float* __restrict__ out, int N)
{
    __shared__ float acc[64 * 136];   // [dstlo][i*16+l4], ch = l4*8+i (bank-staggered)
    __shared__ float wsm[128];        // [dstlo][head]
    __shared__ float ars[128];        // AR staged for the chunk
    const int c = blockIdx.x, tid = threadIdx.x;
    const int base = c * 64;
    for (int i = tid; i < 64 * 136; i += 256) acc[i] = 0.f;
    if (tid < 128) {
        wsm[tid] = 0.f;
        int node2 = base * 2 + tid;
        ars[tid] = (node2 < N * 2) ? AR[node2] : 0.f;
    }
    __syncthreads();

    const int start = B8[c * 8], end = B8[c * 8 + 8];
    const int l4 = tid & 15;          // 16B sub-chunk of the 256B Z row
    const int G  = tid >> 4;          // group 0..15, one edge at a time
    const int h  = l4 >> 3;           // head for these channels
    int p0 = start + G;
    unsigned rec = 0;
    if (p0 < end) rec = edg[p0];
    for (int p = p0; p < end; p += 16) {
        unsigned nrec = 0;
        if (p + 16 < end) nrec = edg[p + 16];
        int dstlo = rec & 63;
        int src = (int)(rec >> 6);
        float al = AL[src * 2 + h];
        float t = al + ars[dstlo * 2 + h];
        t = (t < 0.f) ? NEG_SLOPE * t : t;
        float w = __expf(t);
        uint4 zz = *(const uint4*)(Z + (size_t)src * 128 + l4 * 8);
        float* arow = &acc[dstlo * 136 + l4];
        atomicAdd(&arow[0],   w * bflo(zz.x));
        atomicAdd(&arow[16],  w * bfhi(zz.x));
        atomicAdd(&arow[32],  w * bflo(zz.y));
        atomicAdd(&arow[48],  w * bfhi(zz.y));
        atomicAdd(&arow[64],  w * bflo(zz.z));
        atomicAdd(&arow[80],  w * bfhi(zz.z));
        atomicAdd(&arow[96],  w * bflo(zz.w));
        atomicAdd(&arow[112], w * bfhi(zz.w));
        if ((l4 & 7) == 0) atomicAdd(&wsm[dstlo * 2 + h], w);
        rec = nrec;
    }
    __syncthreads();

    // normalize, head-combine, bias, coalesced write
    for (int idx = tid; idx < 64 * 64; idx += 256) {
        int n = idx >> 6, oc = idx & 63;
        int node = base + n;
        if (node < N) {
            float i0 = 1.f / (wsm[n * 2]     + 1e-16f);
            float i1 = 1.f / (wsm[n * 2 + 1] + 1e-16f);
            float a0 = acc[n * 136 + (oc & 7) * 16 + (oc >> 3)];
            float a1 = acc[n * 136 + (oc & 7) * 16 + (oc >> 3) + 8];
            out[(size_t)node * 64 + oc] = a0 * i0 + a1 * i1 + bias[oc];
        }
    }
}

// ---------------- launch ----------------
extern "C" void kernel_launch(void* const* d_in, const int* in_sizes, int n_in,
                              void* d_out, int out_size, void* d_ws, size_t ws_size,
                              hipStream_t stream)
{
    const float* x    = (const float*)d_in[0];
    const int*   ei   = (const int*)d_in[1];
    const float* Wl   = (const float*)d_in[2];
    const float* attL = (const float*)d_in[3];
    const float* attR = (const float*)d_in[4];
    const float* Wout = (const float*)d_in[5];
    const float* bias = (const float*)d_in[6];
    float* out = (float*)d_out;

    const int N = in_sizes[0] / 128;   // 50000
    const int E = in_sizes[1] / 2;     // 800000
    const int Etot = E + N;
    const int C = (N + 63) >> 6;       // 782 chunks of 64 nodes
    const int NSEG = C * 8;            // 6256 (chunk, class) segments

    char* ws = (char*)d_ws;
    size_t o = 0;
    auto alloc = [&](size_t bytes) {
        void* p = ws + o; o += (bytes + 255) & ~(size_t)255; return p;
    };
    float*          Wc   = (float*)alloc(128 * 128 * 4);
    float*          AV   = (float*)alloc(128 * 4 * 4);
    unsigned short* Z    = (unsigned short*)alloc((size_t)N * 128 * 2);  // 12.8 MB
    float*          AL   = (float*)alloc((size_t)N * 2 * 4);
    float*          AR   = (float*)alloc((size_t)N * 2 * 4);
    int*            CNT8 = (int*)alloc((size_t)NSEG * 4);
    int*            B8   = (int*)alloc((size_t)(NSEG + 1) * 4);
    int*            CPTR = (int*)alloc((size_t)NSEG * 4);
    unsigned*       EDG  = (unsigned*)alloc((size_t)Etot * 4);           // 3.4 MB

    hipMemsetAsync(CNT8, 0, (size_t)NSEG * 4, stream);

    int eb = (Etot + 255) / 256;       // 3321
    int ZB = (N + 63) / 64;            // 782

    prep_count_kernel<<<PREP_B + eb, 256, 0, stream>>>(Wl, Wout, attL, attR,
                                                       Wc, AV, ei, E, Etot, CNT8);
    zproj_scan_kernel<<<ZB + 1, 256, 0, stream>>>(x, Wc, AV, N, ZB, NSEG, Etot,
                                                  Z, AL, AR, CNT8, B8, CPTR);
    fillb_kernel<<<eb, 256, 0, stream>>>(ei, E, Etot, CPTR, EDG);
    aggB_kernel<<<C, 256, 0, stream>>>(B8, EDG, AL, AR, Z, bias, out, N);
}